// Round 2
// baseline (166.512 us; speedup 1.0000x reference)
//
#include <hip/hip_runtime.h>

#define NEG_SLOPE 0.2f
#define MASK_EPS 1e-8f

// ---------------------------------------------------------------------------
// Kernel 1: Wh = h @ W  (B*N=16384 rows, K=128, D_out=128)
//           s_i[row,h] = dot(Wh[row, h*32:(h+1)*32], a_src[h])
//           s_j[row,h] = dot(Wh[row, h*32:(h+1)*32], a_dst[h])
// Block: 256 threads = 8 rows x 32 col-groups (4 cols each).
// ---------------------------------------------------------------------------
__global__ __launch_bounds__(256) void gat_wh_kernel(
    const float* __restrict__ h, const float* __restrict__ W,
    const float* __restrict__ a, float* __restrict__ Wh,
    float* __restrict__ sI, float* __restrict__ sJ) {
  __shared__ float hS[8][128];
  const int tid = threadIdx.x;
  const int row0 = blockIdx.x * 8;

  {
    int r = tid >> 5, c4 = (tid & 31) << 2;
    *(float4*)&hS[r][c4] = *(const float4*)&h[(size_t)(row0 + r) * 128 + c4];
  }
  __syncthreads();

  const int rowl = tid >> 5;
  const int cidx = tid & 31;
  const int c0 = cidx << 2;

  float4 acc = {0.f, 0.f, 0.f, 0.f};
#pragma unroll 8
  for (int k = 0; k < 128; ++k) {
    float hv = hS[rowl][k];
    float4 w4 = *(const float4*)&W[k * 128 + c0];
    acc.x = fmaf(hv, w4.x, acc.x);
    acc.y = fmaf(hv, w4.y, acc.y);
    acc.z = fmaf(hv, w4.z, acc.z);
    acc.w = fmaf(hv, w4.w, acc.w);
  }

  const size_t row = (size_t)row0 + rowl;
  *(float4*)&Wh[row * 128 + c0] = acc;

  const int head = cidx >> 3;
  const int dl = c0 & 31;
  const float* asrc = &a[head * 64];
  const float* adst = &a[head * 64 + 32];
  float pi = acc.x * asrc[dl] + acc.y * asrc[dl + 1] + acc.z * asrc[dl + 2] + acc.w * asrc[dl + 3];
  float pj = acc.x * adst[dl] + acc.y * adst[dl + 1] + acc.z * adst[dl + 2] + acc.w * adst[dl + 3];
#pragma unroll
  for (int off = 1; off < 8; off <<= 1) {
    pi += __shfl_xor(pi, off, 64);
    pj += __shfl_xor(pj, off, 64);
  }
  if ((cidx & 7) == 0) {
    sI[row * 4 + head] = pi;
    sJ[row * 4 + head] = pj;
  }
}

// ---------------------------------------------------------------------------
// Kernel 2: block = (b, j-tile of 16). 256 threads = 4 i-split waves x
// (4 heads x 16 j). Each wave handles 128 i's in 16 chunks of 8, staging
// adj[32][16] + Wh[32][128] (h-rotate-swizzled) per chunk. No max pass
// (e bounded, exp safe in fp32; masked -> p=0 exactly). In-LDS merge of the
// 4 wave-partials at the end.
// ---------------------------------------------------------------------------
__global__ __launch_bounds__(256) void gat_attn_kernel(
    const float* __restrict__ adj, const float* __restrict__ Wh,
    const float* __restrict__ sI, const float* __restrict__ sJ,
    float* __restrict__ out) {
  __shared__ float sIS[2048];      // 8 KB: s_i for all 512 i x 4 h
  __shared__ float arena[4608];    // 18 KB: adjS[32][16] + whS[32][128]; merge: 2*64*33
  __shared__ float lS[4][64];      // 1 KB

  const int tid = threadIdx.x;
  const int b = blockIdx.x;        // 0..31
  const int j0 = blockIdx.y * 16;  // 32 tiles
  const int is = tid >> 6;         // wave id = i-split group
  const int lane = tid & 63;
  const int h = lane >> 4;
  const int jl = lane & 15;
  const int j = j0 + jl;

  float* adjS = arena;             // [32][16]
  float* whS = arena + 512;        // [32][128], h-rotate swizzled

  for (int idx = tid; idx < 2048; idx += 256)
    sIS[idx] = sI[(size_t)b * 2048 + idx];
  const float sJv = sJ[((size_t)b * 512 + j) * 4 + h];

  const float* adjB = adj + (size_t)b * 512 * 512;
  const float* WhB = Wh + (size_t)b * 512 * 128;

  float l = 0.f;
  float accf[32];
#pragma unroll
  for (int d = 0; d < 32; ++d) accf[d] = 0.f;

  for (int t = 0; t < 16; ++t) {
    __syncthreads();
    // stage adj: 32 rows (8 per i-split group) x 16 j, one float2/thread
    {
      int r = tid >> 3, k = (tid & 7) << 1;
      int gi = (r >> 3) * 128 + t * 8 + (r & 7);
      *(float2*)&adjS[r * 16 + k] = *(const float2*)&adjB[(size_t)gi * 512 + j0 + k];
    }
    // stage Wh: 32 rows x 128 d, 4 float4/thread, h-rotate swizzle on dst
#pragma unroll
    for (int u = 0; u < 4; ++u) {
      int idx4 = tid + u * 256;
      int r = idx4 >> 5, cc = idx4 & 31;
      int gi = (r >> 3) * 128 + t * 8 + (r & 7);
      int hof = cc >> 3, qq = cc & 7;
      int dst = r * 128 + hof * 32 + (((qq + hof) & 7) << 2);
      *(float4*)&whS[dst] = *(const float4*)&WhB[(size_t)gi * 128 + cc * 4];
    }
    __syncthreads();
#pragma unroll
    for (int ii = 0; ii < 8; ++ii) {
      int row = (is << 3) + ii;
      int gi = is * 128 + t * 8 + ii;
      float e = sIS[gi * 4 + h] + sJv;
      e = e >= 0.f ? e : NEG_SLOPE * e;
      float av = adjS[row * 16 + jl];
      float p = av > MASK_EPS ? __expf(e) : 0.f;
      l += p;
      const float* wrow = &whS[row * 128 + h * 32];
#pragma unroll
      for (int q = 0; q < 8; ++q) {
        float4 w = *(const float4*)&wrow[((q + h) & 7) << 2];
        accf[q * 4 + 0] = fmaf(p, w.x, accf[q * 4 + 0]);
        accf[q * 4 + 1] = fmaf(p, w.y, accf[q * 4 + 1]);
        accf[q * 4 + 2] = fmaf(p, w.z, accf[q * 4 + 2]);
        accf[q * 4 + 3] = fmaf(p, w.w, accf[q * 4 + 3]);
      }
    }
  }

  // ---- merge the 4 i-split partials (waves) in LDS ----
  lS[is][lane] = l;
  __syncthreads();                 // also: everyone done reading arena
  if (is & 1) {                    // waves 1,3 publish
    float* buf = &arena[(is >> 1) * (64 * 33) + lane * 33];
#pragma unroll
    for (int d = 0; d < 32; ++d) buf[d] = accf[d];
  }
  __syncthreads();
  if (!(is & 1)) {                 // waves 0,2 absorb
    const float* buf = &arena[(is >> 1) * (64 * 33) + lane * 33];
#pragma unroll
    for (int d = 0; d < 32; ++d) accf[d] += buf[d];
  }
  __syncthreads();
  if (is == 2) {                   // wave 2 publishes
    float* buf = &arena[lane * 33];
#pragma unroll
    for (int d = 0; d < 32; ++d) buf[d] = accf[d];
  }
  __syncthreads();
  if (is == 0) {                   // wave 0 finalizes
#pragma unroll
    for (int d = 0; d < 32; ++d) accf[d] += arena[lane * 33 + d];
    const float rl = 1.0f / (lS[0][lane] + lS[1][lane] + lS[2][lane] + lS[3][lane]);
    float* orow = &out[((size_t)b * 512 + j) * 128 + h * 32];
#pragma unroll
    for (int q = 0; q < 8; ++q) {
      float4 v = make_float4(accf[q * 4] * rl, accf[q * 4 + 1] * rl,
                             accf[q * 4 + 2] * rl, accf[q * 4 + 3] * rl);
      *(float4*)&orow[q * 4] = v;
    }
  }
}

extern "C" void kernel_launch(void* const* d_in, const int* in_sizes, int n_in,
                              void* d_out, int out_size, void* d_ws, size_t ws_size,
                              hipStream_t stream) {
  const float* h = (const float*)d_in[0];     // (32, 512, 128)
  const float* adj = (const float*)d_in[1];   // (32, 512, 512)
  const float* W = (const float*)d_in[2];     // (128, 128)
  const float* a = (const float*)d_in[3];     // (4, 64)
  float* out = (float*)d_out;                 // (32, 512, 128)

  const int B = 32, N = 512;
  float* Wh = (float*)d_ws;                   // B*N*128 floats = 8 MB
  float* sI = Wh + (size_t)B * N * 128;
  float* sJ = sI + (size_t)B * N * 4;

  gat_wh_kernel<<<dim3(B * N / 8), dim3(256), 0, stream>>>(h, W, a, Wh, sI, sJ);
  gat_attn_kernel<<<dim3(B, N / 16), dim3(256), 0, stream>>>(adj, Wh, sI, sJ, out);
}

// Round 4
// 71.773 us; speedup vs baseline: 2.3200x; 2.3200x over previous
//
#include <hip/hip_runtime.h>

typedef float f32x4 __attribute__((ext_vector_type(4)));
typedef _Float16 f16x8 __attribute__((ext_vector_type(8)));
typedef __fp16 fp16x2 __attribute__((ext_vector_type(2)));

#define NEG_SLOPE 0.2f
#define MASK_EPS 1e-8f

// ---------------------------------------------------------------------------
// Kernel 1: Wh = h @ W; writes WhT (f16, [b][d=128][i=512]) via LDS transpose,
// plus scores sI_T/sJ_T ([b][h][i], fp32).
// Block: 256 threads = 8 rows x 32 col-groups (4 cols each).
// ---------------------------------------------------------------------------
__global__ __launch_bounds__(256) void gat_wh_kernel(
    const float* __restrict__ h, const float* __restrict__ W,
    const float* __restrict__ a, _Float16* __restrict__ whT,
    float* __restrict__ sIT, float* __restrict__ sJT) {
  __shared__ float hS[8][128];
  __shared__ _Float16 trS[128][16];   // 8 valid i-halfs per d-row, pitch 16
  const int tid = threadIdx.x;
  const int row0 = blockIdx.x * 8;

  {
    int r = tid >> 5, c4 = (tid & 31) << 2;
    *(float4*)&hS[r][c4] = *(const float4*)&h[(size_t)(row0 + r) * 128 + c4];
  }
  __syncthreads();

  const int rowl = tid >> 5;
  const int cidx = tid & 31;
  const int c0 = cidx << 2;

  float4 acc = {0.f, 0.f, 0.f, 0.f};
#pragma unroll 8
  for (int k = 0; k < 128; ++k) {
    float hv = hS[rowl][k];
    float4 w4 = *(const float4*)&W[k * 128 + c0];
    acc.x = fmaf(hv, w4.x, acc.x);
    acc.y = fmaf(hv, w4.y, acc.y);
    acc.z = fmaf(hv, w4.z, acc.z);
    acc.w = fmaf(hv, w4.w, acc.w);
  }

  const int row = row0 + rowl;           // global i-row (b*512 + n)
  const int bb = row >> 9;
  const int nloc = row & 511;

  // head scores (fp32, full precision)
  const int head = cidx >> 3;
  const int dl = c0 & 31;
  const float* asrc = &a[head * 64];
  const float* adst = &a[head * 64 + 32];
  float pi = acc.x * asrc[dl] + acc.y * asrc[dl + 1] + acc.z * asrc[dl + 2] + acc.w * asrc[dl + 3];
  float pj = acc.x * adst[dl] + acc.y * adst[dl + 1] + acc.z * adst[dl + 2] + acc.w * adst[dl + 3];
#pragma unroll
  for (int off = 1; off < 8; off <<= 1) {
    pi += __shfl_xor(pi, off, 64);
    pj += __shfl_xor(pj, off, 64);
  }
  if ((cidx & 7) == 0) {
    sIT[bb * 2048 + head * 512 + nloc] = pi;
    sJT[bb * 2048 + head * 512 + nloc] = pj;
  }

  // transpose Wh -> f16 in LDS
  trS[c0 + 0][rowl] = (_Float16)acc.x;
  trS[c0 + 1][rowl] = (_Float16)acc.y;
  trS[c0 + 2][rowl] = (_Float16)acc.z;
  trS[c0 + 3][rowl] = (_Float16)acc.w;
  __syncthreads();

  if (tid < 128) {
    const int d = tid;
    const int i0 = row0 & 511;
    float4 v = *(const float4*)&trS[d][0];   // 8 halfs = 16B
    *(float4*)&whT[((size_t)(row0 >> 9) * 128 + d) * 512 + i0] = v;
  }
}

// ---------------------------------------------------------------------------
// Kernel 2: block = (b, 32-j tile); 4 waves = 4 heads. Per 32-i k-step each
// lane builds its MFMA A-fragment of P (8 p's: adj direct-from-global,
// s-scores from LDS, exp in fp32, cvt_pkrtz to f16) and MFMAs against WhT
// fragments from LDS (pitch-72 halfs). adj+WhT double-buffered in registers.
// ---------------------------------------------------------------------------
__global__ __launch_bounds__(256) void gat_attn_kernel(
    const float* __restrict__ adj, const _Float16* __restrict__ whT,
    const float* __restrict__ sIT, const float* __restrict__ sJT,
    float* __restrict__ out) {
  __shared__ _Float16 whS[128 * 72];   // [d=128][i=64], pitch 72 halfs
  __shared__ float sIS[4 * 512];       // [h][i]

  const int tid = threadIdx.x;
  const int b = blockIdx.x;            // 0..31
  const int j0 = blockIdx.y * 32;      // 16 tiles
  const int wv = tid >> 6;             // wave = head
  const int lane = tid & 63;
  const int nl = lane & 15;
  const int ig = lane >> 4;

  for (int idx = tid; idx < 2048; idx += 256)
    sIS[idx] = sIT[b * 2048 + idx];

  const float sj0 = sJT[b * 2048 + wv * 512 + j0 + nl];
  const float sj1 = sJT[b * 2048 + wv * 512 + j0 + 16 + nl];

  const float* adjP = adj + (size_t)b * 512 * 512;
  const _Float16* whP = whT + (size_t)b * 128 * 512;

  const int sr = tid >> 3;             // staging row 0..31 (+u*32)
  const int sc = tid & 7;              // staging col-8 group

  f32x4 acc00 = {0.f,0.f,0.f,0.f}, acc01 = {0.f,0.f,0.f,0.f};
  f32x4 acc10 = {0.f,0.f,0.f,0.f}, acc11 = {0.f,0.f,0.f,0.f};
  float l0 = 0.f, l1 = 0.f;

  const int aoff = (ig * 8) * 512 + j0 + nl;

  float4 whReg[2][4];
  float adjReg[2][32];                 // [buf][ks*16 + js*8 + r]

  // prologue: issue tile-0 loads
#pragma unroll
  for (int u = 0; u < 4; ++u)
    whReg[0][u] = *(const float4*)(whP + (size_t)(sr + u * 32) * 512 + sc * 8);
#pragma unroll
  for (int ks2 = 0; ks2 < 2; ++ks2)
#pragma unroll
    for (int js = 0; js < 2; ++js)
#pragma unroll
      for (int r = 0; r < 8; ++r)
        adjReg[0][ks2 * 16 + js * 8 + r] = adjP[aoff + (ks2 * 32 + r) * 512 + js * 16];

#pragma unroll 2
  for (int t = 0; t < 8; ++t) {
    const int cur = t & 1, nxt = cur ^ 1;
    __syncthreads();                   // whS free
#pragma unroll
    for (int u = 0; u < 4; ++u)
      *(float4*)((_Float16*)whS + (sr + u * 32) * 72 + sc * 8) = whReg[cur][u];
    __syncthreads();

    if (t < 7) {                       // issue tile t+1 loads (hide under compute)
#pragma unroll
      for (int u = 0; u < 4; ++u)
        whReg[nxt][u] = *(const float4*)(whP + (size_t)(sr + u * 32) * 512 + (t + 1) * 64 + sc * 8);
#pragma unroll
      for (int ks2 = 0; ks2 < 2; ++ks2)
#pragma unroll
        for (int js = 0; js < 2; ++js)
#pragma unroll
          for (int r = 0; r < 8; ++r)
            adjReg[nxt][ks2 * 16 + js * 8 + r] =
                adjP[aoff + ((t + 1) * 64 + ks2 * 32 + r) * 512 + js * 16];
    }

#pragma unroll
    for (int ks = 0; ks < 2; ++ks) {
      float si[8];
      {
        float4 sA = *(const float4*)&sIS[wv * 512 + t * 64 + ks * 32 + ig * 8];
        float4 sB = *(const float4*)&sIS[wv * 512 + t * 64 + ks * 32 + ig * 8 + 4];
        si[0]=sA.x; si[1]=sA.y; si[2]=sA.z; si[3]=sA.w;
        si[4]=sB.x; si[5]=sB.y; si[6]=sB.z; si[7]=sB.w;
      }
      const f16x8 bf0 = *(const f16x8*)&whS[(wv * 32 + nl) * 72 + ks * 32 + ig * 8];
      const f16x8 bf1 = *(const f16x8*)&whS[(wv * 32 + 16 + nl) * 72 + ks * 32 + ig * 8];

#pragma unroll
      for (int js = 0; js < 2; ++js) {
        const float sjv = js ? sj1 : sj0;
        float p[8];
        float lsum = 0.f;
#pragma unroll
        for (int r = 0; r < 8; ++r) {
          float e = si[r] + sjv;
          e = e >= 0.f ? e : NEG_SLOPE * e;
          float av = adjReg[cur][ks * 16 + js * 8 + r];
          p[r] = av > MASK_EPS ? __expf(e) : 0.f;
          lsum += p[r];
        }
        if (js) l1 += lsum; else l0 += lsum;

        union { fp16x2 h2[4]; f16x8 v; } af;
#pragma unroll
        for (int q = 0; q < 4; ++q)
          af.h2[q] = __builtin_amdgcn_cvt_pkrtz(p[2 * q], p[2 * q + 1]);

        if (js == 0) {
          acc00 = __builtin_amdgcn_mfma_f32_16x16x32_f16(af.v, bf0, acc00, 0, 0, 0);
          acc01 = __builtin_amdgcn_mfma_f32_16x16x32_f16(af.v, bf1, acc01, 0, 0, 0);
        } else {
          acc10 = __builtin_amdgcn_mfma_f32_16x16x32_f16(af.v, bf0, acc10, 0, 0, 0);
          acc11 = __builtin_amdgcn_mfma_f32_16x16x32_f16(af.v, bf1, acc11, 0, 0, 0);
        }
      }
    }
  }

  // reduce l over the 4 ig-slices
  l0 += __shfl_xor(l0, 16, 64); l0 += __shfl_xor(l0, 32, 64);
  l1 += __shfl_xor(l1, 16, 64); l1 += __shfl_xor(l1, 32, 64);

  // D layout: row(m=j_local) = 4*ig + reg, col(n=d_lo) = nl
  float* outB = out + ((size_t)b * 512 + j0) * 128 + wv * 32;
#pragma unroll
  for (int reg = 0; reg < 4; ++reg) {
    const int jr = 4 * ig + reg;
    {
      float rl = 1.0f / __shfl(l0, jr, 64);
      outB[(size_t)jr * 128 + nl]      = acc00[reg] * rl;
      outB[(size_t)jr * 128 + 16 + nl] = acc01[reg] * rl;
    }
    {
      float rl = 1.0f / __shfl(l1, jr, 64);
      outB[(size_t)(16 + jr) * 128 + nl]      = acc10[reg] * rl;
      outB[(size_t)(16 + jr) * 128 + 16 + nl] = acc11[reg] * rl;
    }
  }
}

extern "C" void kernel_launch(void* const* d_in, const int* in_sizes, int n_in,
                              void* d_out, int out_size, void* d_ws, size_t ws_size,
                              hipStream_t stream) {
  const float* h = (const float*)d_in[0];     // (32, 512, 128)
  const float* adj = (const float*)d_in[1];   // (32, 512, 512)
  const float* W = (const float*)d_in[2];     // (128, 128)
  const float* a = (const float*)d_in[3];     // (4, 64)
  float* out = (float*)d_out;                 // (32, 512, 128)

  _Float16* whT = (_Float16*)d_ws;                    // 32*128*512 halfs = 4 MB
  float* sIT = (float*)(whT + (size_t)32 * 128 * 512);  // 32*4*512 f32
  float* sJT = sIT + (size_t)32 * 4 * 512;

  gat_wh_kernel<<<dim3(2048), dim3(256), 0, stream>>>(h, W, a, whT, sIT, sJT);
  gat_attn_kernel<<<dim3(32, 16), dim3(256), 0, stream>>>(adj, whT, sIT, sJT, out);
}

// Round 5
// 64.776 us; speedup vs baseline: 2.5706x; 1.1080x over previous
//
#include <hip/hip_runtime.h>

typedef float f32x4 __attribute__((ext_vector_type(4)));
typedef _Float16 f16x8 __attribute__((ext_vector_type(8)));
typedef __fp16 fp16x2 __attribute__((ext_vector_type(2)));

#define NEG_SLOPE 0.2f
#define MASK_EPS 1e-8f

// ---------------------------------------------------------------------------
// Kernel 1: Wh = h @ W; writes WhT (f16, [b][d=128][i=512]) via LDS transpose,
// plus scores sI_T/sJ_T ([b][h][i], fp32).  (unchanged from round 4)
// ---------------------------------------------------------------------------
__global__ __launch_bounds__(256) void gat_wh_kernel(
    const float* __restrict__ h, const float* __restrict__ W,
    const float* __restrict__ a, _Float16* __restrict__ whT,
    float* __restrict__ sIT, float* __restrict__ sJT) {
  __shared__ float hS[8][128];
  __shared__ _Float16 trS[128][16];   // 8 valid i-halfs per d-row, pitch 16
  const int tid = threadIdx.x;
  const int row0 = blockIdx.x * 8;

  {
    int r = tid >> 5, c4 = (tid & 31) << 2;
    *(float4*)&hS[r][c4] = *(const float4*)&h[(size_t)(row0 + r) * 128 + c4];
  }
  __syncthreads();

  const int rowl = tid >> 5;
  const int cidx = tid & 31;
  const int c0 = cidx << 2;

  float4 acc = {0.f, 0.f, 0.f, 0.f};
#pragma unroll 8
  for (int k = 0; k < 128; ++k) {
    float hv = hS[rowl][k];
    float4 w4 = *(const float4*)&W[k * 128 + c0];
    acc.x = fmaf(hv, w4.x, acc.x);
    acc.y = fmaf(hv, w4.y, acc.y);
    acc.z = fmaf(hv, w4.z, acc.z);
    acc.w = fmaf(hv, w4.w, acc.w);
  }

  const int row = row0 + rowl;           // global i-row (b*512 + n)
  const int bb = row >> 9;
  const int nloc = row & 511;

  const int head = cidx >> 3;
  const int dl = c0 & 31;
  const float* asrc = &a[head * 64];
  const float* adst = &a[head * 64 + 32];
  float pi = acc.x * asrc[dl] + acc.y * asrc[dl + 1] + acc.z * asrc[dl + 2] + acc.w * asrc[dl + 3];
  float pj = acc.x * adst[dl] + acc.y * adst[dl + 1] + acc.z * adst[dl + 2] + acc.w * adst[dl + 3];
#pragma unroll
  for (int off = 1; off < 8; off <<= 1) {
    pi += __shfl_xor(pi, off, 64);
    pj += __shfl_xor(pj, off, 64);
  }
  if ((cidx & 7) == 0) {
    sIT[bb * 2048 + head * 512 + nloc] = pi;
    sJT[bb * 2048 + head * 512 + nloc] = pj;
  }

  trS[c0 + 0][rowl] = (_Float16)acc.x;
  trS[c0 + 1][rowl] = (_Float16)acc.y;
  trS[c0 + 2][rowl] = (_Float16)acc.z;
  trS[c0 + 3][rowl] = (_Float16)acc.w;
  __syncthreads();

  if (tid < 128) {
    const int d = tid;
    const int i0 = row0 & 511;
    float4 v = *(const float4*)&trS[d][0];   // 8 halfs = 16B
    *(float4*)&whT[((size_t)(row0 >> 9) * 128 + d) * 512 + i0] = v;
  }
}

// ---------------------------------------------------------------------------
// Kernel 2: block = (b, 16-j tile); 4 waves = 4 heads; ZERO LDS, zero
// barriers. Per 64-i t-step: adj double-buffered in regs (HBM/L3 stream);
// s_i + WhT B-fragments loaded direct from global (L2-resident); p built in
// fp32 (exp, lrelu, mask), packed f16, MFMA 16x16x32 accumulate.
// ---------------------------------------------------------------------------
__global__ __launch_bounds__(256, 4) void gat_attn_kernel(
    const float* __restrict__ adj, const _Float16* __restrict__ whT,
    const float* __restrict__ sIT, const float* __restrict__ sJT,
    float* __restrict__ out) {
  const int tid = threadIdx.x;
  const int b = blockIdx.x;            // 0..31
  const int j0 = blockIdx.y * 16;      // 32 tiles
  const int wv = tid >> 6;             // wave = head
  const int lane = tid & 63;
  const int nl = lane & 15;
  const int ig = lane >> 4;

  const float sj = sJT[b * 2048 + wv * 512 + j0 + nl];

  const float* adjP = adj + (size_t)b * 512 * 512 + (size_t)(ig * 8) * 512 + j0 + nl;
  const _Float16* whP = whT + (size_t)b * 128 * 512 + (size_t)(wv * 32 + nl) * 512 + ig * 8;
  const float* siP = sIT + b * 2048 + wv * 512 + ig * 8;

  f32x4 acc0 = {0.f, 0.f, 0.f, 0.f};
  f32x4 acc1 = {0.f, 0.f, 0.f, 0.f};
  float l = 0.f;

  float adjReg[2][16];                 // [buf][ks*8 + r]

  // prologue: tile-0 adj
#pragma unroll
  for (int ks = 0; ks < 2; ++ks)
#pragma unroll
    for (int r = 0; r < 8; ++r)
      adjReg[0][ks * 8 + r] = adjP[(size_t)(ks * 32 + r) * 512];

#pragma unroll 2
  for (int t = 0; t < 8; ++t) {
    const int cur = t & 1;
    if (t < 7) {                       // prefetch next tile's adj
#pragma unroll
      for (int ks = 0; ks < 2; ++ks)
#pragma unroll
        for (int r = 0; r < 8; ++r)
          adjReg[cur ^ 1][ks * 8 + r] =
              adjP[(size_t)((t + 1) * 64 + ks * 32 + r) * 512];
    }

    // direct-from-global fragments (L2-resident)
    f32x4 siA0 = *(const f32x4*)(siP + t * 64);
    f32x4 siB0 = *(const f32x4*)(siP + t * 64 + 4);
    f32x4 siA1 = *(const f32x4*)(siP + t * 64 + 32);
    f32x4 siB1 = *(const f32x4*)(siP + t * 64 + 36);
    f16x8 bf00 = *(const f16x8*)(whP + t * 64);
    f16x8 bf01 = *(const f16x8*)(whP + 16 * 512 + t * 64);
    f16x8 bf10 = *(const f16x8*)(whP + t * 64 + 32);
    f16x8 bf11 = *(const f16x8*)(whP + 16 * 512 + t * 64 + 32);

#pragma unroll
    for (int ks = 0; ks < 2; ++ks) {
      float si[8];
      if (ks == 0) {
        si[0]=siA0.x; si[1]=siA0.y; si[2]=siA0.z; si[3]=siA0.w;
        si[4]=siB0.x; si[5]=siB0.y; si[6]=siB0.z; si[7]=siB0.w;
      } else {
        si[0]=siA1.x; si[1]=siA1.y; si[2]=siA1.z; si[3]=siA1.w;
        si[4]=siB1.x; si[5]=siB1.y; si[6]=siB1.z; si[7]=siB1.w;
      }

      float p[8];
#pragma unroll
      for (int r = 0; r < 8; ++r) {
        float e = si[r] + sj;
        e = e >= 0.f ? e : NEG_SLOPE * e;
        float av = adjReg[cur][ks * 8 + r];
        p[r] = av > MASK_EPS ? __expf(e) : 0.f;
        l += p[r];
      }

      union { fp16x2 h2[4]; f16x8 v; } af;
#pragma unroll
      for (int q = 0; q < 4; ++q)
        af.h2[q] = __builtin_amdgcn_cvt_pkrtz(p[2 * q], p[2 * q + 1]);

      if (ks == 0) {
        acc0 = __builtin_amdgcn_mfma_f32_16x16x32_f16(af.v, bf00, acc0, 0, 0, 0);
        acc1 = __builtin_amdgcn_mfma_f32_16x16x32_f16(af.v, bf01, acc1, 0, 0, 0);
      } else {
        acc0 = __builtin_amdgcn_mfma_f32_16x16x32_f16(af.v, bf10, acc0, 0, 0, 0);
        acc1 = __builtin_amdgcn_mfma_f32_16x16x32_f16(af.v, bf11, acc1, 0, 0, 0);
      }
    }
  }

  // reduce l over the 4 ig-slices -> every lane has l for j = j0 + nl
  l += __shfl_xor(l, 16, 64);
  l += __shfl_xor(l, 32, 64);

  // D layout: row(m=j_local) = 4*ig + reg, col(n=d_lo) = nl
  float* outB = out + ((size_t)b * 512 + j0) * 128 + wv * 32;
#pragma unroll
  for (int reg = 0; reg < 4; ++reg) {
    const int jr = 4 * ig + reg;
    const float rl = 1.0f / __shfl(l, jr, 64);
    outB[(size_t)jr * 128 + nl]      = acc0[reg] * rl;
    outB[(size_t)jr * 128 + 16 + nl] = acc1[reg] * rl;
  }
}

extern "C" void kernel_launch(void* const* d_in, const int* in_sizes, int n_in,
                              void* d_out, int out_size, void* d_ws, size_t ws_size,
                              hipStream_t stream) {
  const float* h = (const float*)d_in[0];     // (32, 512, 128)
  const float* adj = (const float*)d_in[1];   // (32, 512, 512)
  const float* W = (const float*)d_in[2];     // (128, 128)
  const float* a = (const float*)d_in[3];     // (4, 64)
  float* out = (float*)d_out;                 // (32, 512, 128)

  _Float16* whT = (_Float16*)d_ws;                      // 32*128*512 halfs = 4 MB
  float* sIT = (float*)(whT + (size_t)32 * 128 * 512);  // 32*4*512 f32
  float* sJT = sIT + (size_t)32 * 4 * 512;

  gat_wh_kernel<<<dim3(2048), dim3(256), 0, stream>>>(h, W, a, whT, sIT, sJT);
  gat_attn_kernel<<<dim3(32, 32), dim3(256), 0, stream>>>(adj, whT, sIT, sJT, out);
}